// Round 3
// baseline (3559.093 us; speedup 1.0000x reference)
//
#include <hip/hip_runtime.h>

typedef __attribute__((ext_vector_type(8))) short short8v;
typedef __attribute__((ext_vector_type(4))) float f32x4;

#define B_ 32
#define C_ 128
#define J_ 24
#define T_ 128
#define Q_ 6
#define K_ 1024
#define JT (J_*T_)          // 3072
#define M_ (B_*JT)          // 98304

#define OUT_QUANT 0
#define OUT_IDX   12582912
#define OUT_LOSS  13172736
#define OUT_PERP  13172737

#define TAU 0.02f

__device__ __forceinline__ unsigned short f2bf(float f) {
    unsigned int u = __float_as_uint(f);
    u = (u + 0x7FFFu + ((u >> 16) & 1u)) >> 16;
    return (unsigned short)u;
}
__device__ __forceinline__ float bf2f(unsigned short h) {
    return __uint_as_float(((unsigned int)h) << 16);
}

// ---------------- c2: per-code squared norms (fp32 codebook) ----------------
__global__ __launch_bounds__(256) void c2_kernel(const float* __restrict__ cb,
                                                 float* __restrict__ c2) {
    int wave = (blockIdx.x * blockDim.x + threadIdx.x) >> 6;
    int lane = threadIdx.x & 63;
    if (wave >= Q_ * K_) return;
    const float2 v = reinterpret_cast<const float2*>(cb + (size_t)wave * C_)[lane];
    float s = v.x * v.x + v.y * v.y;
    #pragma unroll
    for (int off = 32; off; off >>= 1) s += __shfl_down(s, off, 64);
    if (lane == 0) c2[wave] = s;
}

// ---------------- codebook fp32 -> bf16 hi/lo split ----------------
__global__ __launch_bounds__(256) void cbsplit_kernel(const float* __restrict__ cb,
                                                      unsigned short* __restrict__ h,
                                                      unsigned short* __restrict__ l) {
    int i = blockIdx.x * 256 + threadIdx.x;
    if (i >= Q_ * K_ * C_) return;
    float f = cb[i];
    unsigned short hh = f2bf(f);
    h[i] = hh;
    l[i] = f2bf(f - bf2f(hh));
}

// ---------------- transpose x (B,C,J,T) -> res (M,C) ----------------
__global__ __launch_bounds__(256) void transpose_kernel(const float* __restrict__ x,
                                                        float* __restrict__ res) {
    __shared__ float tile[32][33];
    const int tx = threadIdx.x & 31, ty = threadIdx.x >> 5;
    const int jt0 = blockIdx.x * 32;
    const int c0 = blockIdx.y * 32;
    const int b = blockIdx.z;
    const float* xb = x + ((size_t)b * C_ + c0) * JT + jt0;
    #pragma unroll
    for (int i = 0; i < 4; ++i) {
        int cc = ty + 8 * i;
        tile[cc][tx] = xb[(size_t)cc * JT + tx];
    }
    __syncthreads();
    float* rb = res + ((size_t)b * JT + jt0) * C_ + c0;
    #pragma unroll
    for (int i = 0; i < 4; ++i) {
        int jj = ty + 8 * i;
        rb[(size_t)jj * C_ + tx] = tile[tx][jj];
    }
}

// ---------------- fused VQ stage: MFMA argmin + fp64 refine + update ----------------
__global__ __launch_bounds__(256, 2) void vq_stage_kernel(
        float* __restrict__ res, const float* __restrict__ cb,
        const unsigned short* __restrict__ cb_h, const unsigned short* __restrict__ cb_l,
        const float* __restrict__ c2,
        int* __restrict__ idxws, int* __restrict__ counts,
        float* __restrict__ partials, int q) {
    __shared__ __attribute__((aligned(16))) unsigned short a_h[64 * 128];
    __shared__ __attribute__((aligned(16))) unsigned short a_l[64 * 128];
    __shared__ float c2_lds[1024];
    __shared__ float r2_lds[64];
    __shared__ float wred_d[4 * 64];
    __shared__ float wred_d2[4 * 64];
    __shared__ int wred_i[4 * 64];
    __shared__ int idx_lds[64];
    __shared__ int flaglist[64];
    __shared__ int nflag;
    __shared__ double dred[256];
    __shared__ int dredi[256];
    __shared__ __attribute__((aligned(16))) float rowf[128];
    __shared__ float wsum[4];

    const int t = threadIdx.x;
    const int l = t & 63, w = t >> 6;
    const int m0 = blockIdx.x * 64;
    if (t == 0) nflag = 0;

    // ---- stage A-tile: fp32 res -> bf16 hi/lo, swizzled; + per-row sqnorm ----
    {
        const int r = t >> 2, c0 = (t & 3) << 5;
        const float4* src = (const float4*)(res + (size_t)(m0 + r) * C_ + c0);
        float sq = 0.f;
        #pragma unroll
        for (int i = 0; i < 4; ++i) {
            float4 f0 = src[2 * i], f1 = src[2 * i + 1];
            short8v vh, vl;
#define CNV(slot, val) { float _v = (val); sq += _v * _v; unsigned short _h = f2bf(_v); \
                         vh[slot] = (short)_h; vl[slot] = (short)f2bf(_v - bf2f(_h)); }
            CNV(0, f0.x) CNV(1, f0.y) CNV(2, f0.z) CNV(3, f0.w)
            CNV(4, f1.x) CNV(5, f1.y) CNV(6, f1.z) CNV(7, f1.w)
#undef CNV
            const int off = (c0 + i * 8) ^ ((r & 7) << 3);
            *(short8v*)&a_h[r * 128 + off] = vh;
            *(short8v*)&a_l[r * 128 + off] = vl;
        }
        sq += __shfl_xor(sq, 1);
        sq += __shfl_xor(sq, 2);
        if ((t & 3) == 0) r2_lds[r] = sq;
        for (int i = t; i < K_; i += 256) c2_lds[i] = c2[q * K_ + i];
    }
    __syncthreads();

    // ---- load A fragments (hi) into registers ----
    const int asw0 = (l >> 4) * 8;
    short8v ah[4][4];
    #pragma unroll
    for (int mf = 0; mf < 4; ++mf) {
        const int rowb = (mf * 16 + (l & 15)) * 128;
        #pragma unroll
        for (int ks = 0; ks < 4; ++ks) {
            const int off = (ks * 32 + asw0) ^ ((l & 7) << 3);
            ah[mf][ks] = *(const short8v*)&a_h[rowb + off];
        }
    }
    float r2s[16];
    #pragma unroll
    for (int mf = 0; mf < 4; ++mf)
        #pragma unroll
        for (int rg = 0; rg < 4; ++rg)
            r2s[mf * 4 + rg] = r2_lds[mf * 16 + (l >> 4) * 4 + rg];

    float bd[16], bd2[16];
    int bi[16];
    #pragma unroll
    for (int s = 0; s < 16; ++s) { bd[s] = 3.4e38f; bd2[s] = 3.4e38f; bi[s] = 0; }

    const size_t cbbase = ((size_t)q * K_ + w * 256) * C_ + asw0;
    const unsigned short* __restrict__ ph = cb_h + cbbase;
    const unsigned short* __restrict__ pl = cb_l + cbbase;

    for (int nt = 0; nt < 16; ++nt) {
        const int code = w * 256 + nt * 16 + (l & 15);
        const unsigned short* bph = ph + (size_t)(nt * 16 + (l & 15)) * C_;
        const unsigned short* bpl = pl + (size_t)(nt * 16 + (l & 15)) * C_;

        f32x4 acc0 = {0.f, 0.f, 0.f, 0.f}, acc1 = acc0, acc2 = acc0, acc3 = acc0;
        #pragma unroll
        for (int ks = 0; ks < 4; ++ks) {
            const short8v bh = *(const short8v*)(bph + ks * 32);
            const short8v bl = *(const short8v*)(bpl + ks * 32);
            const int off = (ks * 32 + asw0) ^ ((l & 7) << 3);
            const short8v al0 = *(const short8v*)&a_l[(0 * 16 + (l & 15)) * 128 + off];
            const short8v al1 = *(const short8v*)&a_l[(1 * 16 + (l & 15)) * 128 + off];
            const short8v al2 = *(const short8v*)&a_l[(2 * 16 + (l & 15)) * 128 + off];
            const short8v al3 = *(const short8v*)&a_l[(3 * 16 + (l & 15)) * 128 + off];
            acc0 = __builtin_amdgcn_mfma_f32_16x16x32_bf16(ah[0][ks], bh, acc0, 0, 0, 0);
            acc1 = __builtin_amdgcn_mfma_f32_16x16x32_bf16(ah[1][ks], bh, acc1, 0, 0, 0);
            acc2 = __builtin_amdgcn_mfma_f32_16x16x32_bf16(ah[2][ks], bh, acc2, 0, 0, 0);
            acc3 = __builtin_amdgcn_mfma_f32_16x16x32_bf16(ah[3][ks], bh, acc3, 0, 0, 0);
            acc0 = __builtin_amdgcn_mfma_f32_16x16x32_bf16(al0, bh, acc0, 0, 0, 0);
            acc1 = __builtin_amdgcn_mfma_f32_16x16x32_bf16(al1, bh, acc1, 0, 0, 0);
            acc2 = __builtin_amdgcn_mfma_f32_16x16x32_bf16(al2, bh, acc2, 0, 0, 0);
            acc3 = __builtin_amdgcn_mfma_f32_16x16x32_bf16(al3, bh, acc3, 0, 0, 0);
            acc0 = __builtin_amdgcn_mfma_f32_16x16x32_bf16(ah[0][ks], bl, acc0, 0, 0, 0);
            acc1 = __builtin_amdgcn_mfma_f32_16x16x32_bf16(ah[1][ks], bl, acc1, 0, 0, 0);
            acc2 = __builtin_amdgcn_mfma_f32_16x16x32_bf16(ah[2][ks], bl, acc2, 0, 0, 0);
            acc3 = __builtin_amdgcn_mfma_f32_16x16x32_bf16(ah[3][ks], bl, acc3, 0, 0, 0);
        }
        const float c2v = c2_lds[code];
#define UPD(accv, mf, rg) { \
            float d = fmaf(-2.f, accv[rg], r2s[mf * 4 + rg]) + c2v; \
            bool lt = d < bd[mf * 4 + rg]; \
            bd2[mf * 4 + rg] = lt ? bd[mf * 4 + rg] : fminf(bd2[mf * 4 + rg], d); \
            bd[mf * 4 + rg] = lt ? d : bd[mf * 4 + rg]; \
            bi[mf * 4 + rg] = lt ? code : bi[mf * 4 + rg]; }
        UPD(acc0, 0, 0) UPD(acc0, 0, 1) UPD(acc0, 0, 2) UPD(acc0, 0, 3)
        UPD(acc1, 1, 0) UPD(acc1, 1, 1) UPD(acc1, 1, 2) UPD(acc1, 1, 3)
        UPD(acc2, 2, 0) UPD(acc2, 2, 1) UPD(acc2, 2, 2) UPD(acc2, 2, 3)
        UPD(acc3, 3, 0) UPD(acc3, 3, 1) UPD(acc3, 3, 2) UPD(acc3, 3, 3)
#undef UPD
    }

    // ---- cross-lane reduce (16 code-lanes per row) ----
    #pragma unroll
    for (int s = 0; s < 16; ++s) {
        float d1 = bd[s], d2 = bd2[s];
        int i1 = bi[s];
        #pragma unroll
        for (int off = 1; off < 16; off <<= 1) {
            float od1 = __shfl_xor(d1, off);
            float od2 = __shfl_xor(d2, off);
            int oi1 = __shfl_xor(i1, off);
            float nd2 = fminf(fminf(d2, od2), fmaxf(d1, od1));
            if (od1 < d1 || (od1 == d1 && oi1 < i1)) { d1 = od1; i1 = oi1; }
            d2 = nd2;
        }
        if ((l & 15) == 0) {
            const int row = (s >> 2) * 16 + (l >> 4) * 4 + (s & 3);
            wred_d[w * 64 + row] = d1;
            wred_d2[w * 64 + row] = d2;
            wred_i[w * 64 + row] = i1;
        }
    }
    __syncthreads();

    // ---- cross-wave merge + near-tie flag ----
    if (t < 64) {
        float D1 = wred_d[t], D2 = wred_d2[t];
        int I1 = wred_i[t];
        #pragma unroll
        for (int ww = 1; ww < 4; ++ww) {
            float od1 = wred_d[ww * 64 + t];
            float od2 = wred_d2[ww * 64 + t];
            int oi1 = wred_i[ww * 64 + t];
            float nd2 = fminf(fminf(D2, od2), fmaxf(D1, od1));
            if (od1 < D1 || (od1 == D1 && oi1 < I1)) { D1 = od1; I1 = oi1; }
            D2 = nd2;
        }
        idx_lds[t] = I1;
        if (D2 - D1 < TAU) { int p = atomicAdd(&nflag, 1); flaglist[p] = t; }
    }
    __syncthreads();

    // ---- fp64 refinement for near-ties (exact fp32 residual from global) ----
    for (int f = 0; f < nflag; ++f) {
        const int r = flaglist[f];
        if (t < 32) ((float4*)rowf)[t] = ((const float4*)(res + (size_t)(m0 + r) * C_))[t];
        __syncthreads();
        double bdd = 1e300;
        int bk = 0;
        #pragma unroll
        for (int kk = 0; kk < 4; ++kk) {
            const int k = t + kk * 256;
            const float4* bp4 = (const float4*)(cb + ((size_t)q * K_ + k) * C_);
            const float4* rf4 = (const float4*)rowf;
            double s = 0.0;
            for (int c4 = 0; c4 < 32; ++c4) {
                float4 bv = bp4[c4];
                float4 rv = rf4[c4];
                double d0 = (double)rv.x - (double)bv.x; s = fma(d0, d0, s);
                double d1 = (double)rv.y - (double)bv.y; s = fma(d1, d1, s);
                double d2 = (double)rv.z - (double)bv.z; s = fma(d2, d2, s);
                double d3 = (double)rv.w - (double)bv.w; s = fma(d3, d3, s);
            }
            if (s < bdd || (s == bdd && k < bk)) { bdd = s; bk = k; }
        }
        dred[t] = bdd; dredi[t] = bk;
        __syncthreads();
        for (int o = 128; o; o >>= 1) {
            if (t < o) {
                double dv = dred[t + o]; int kv = dredi[t + o];
                if (dv < dred[t] || (dv == dred[t] && kv < dredi[t])) {
                    dred[t] = dv; dredi[t] = kv;
                }
            }
            __syncthreads();
        }
        if (t == 0) idx_lds[r] = dredi[0];
        __syncthreads();
    }

    if (t < 64) idxws[(size_t)q * M_ + m0 + t] = idx_lds[t];

    // ---- fused update: residual, loss partial, histogram ----
    {
        const int r = t >> 2, c0 = (t & 3) << 5;
        const int k = idx_lds[r];
        const float* __restrict__ cbr = cb + ((size_t)q * K_ + k) * C_ + c0;
        float* rp = res + (size_t)(m0 + r) * C_ + c0;
        float sq = 0.f;
        #pragma unroll
        for (int i = 0; i < 8; ++i) {
            float4 rv = ((const float4*)rp)[i];
            float4 cv = ((const float4*)cbr)[i];
            float dx = rv.x - cv.x, dy = rv.y - cv.y, dz = rv.z - cv.z, dw = rv.w - cv.w;
            sq += dx * dx + dy * dy + dz * dz + dw * dw;
            float4 nr;
            nr.x = rv.x - (rv.x + (cv.x - rv.x));
            nr.y = rv.y - (rv.y + (cv.y - rv.y));
            nr.z = rv.z - (rv.z + (cv.z - rv.z));
            nr.w = rv.w - (rv.w + (cv.w - rv.w));
            ((float4*)rp)[i] = nr;
        }
        if ((t & 3) == 0) atomicAdd(&counts[q * K_ + k], 1);
        #pragma unroll
        for (int off = 32; off; off >>= 1) sq += __shfl_down(sq, off, 64);
        if (l == 0) wsum[w] = sq;
    }
    __syncthreads();
    if (t == 0) partials[q * 1536 + blockIdx.x] = wsum[0] + wsum[1] + wsum[2] + wsum[3];
}

// ---------------- scalars: loss + perplexity ----------------
__global__ __launch_bounds__(256) void scalars_kernel(const float* __restrict__ partials,
                                                      const int* __restrict__ counts,
                                                      float* __restrict__ out) {
    __shared__ float red[256];
    const int t = threadIdx.x;
    float loss_acc = 0.f, perp_acc = 0.f;
    for (int q = 0; q < Q_; ++q) {
        float s = 0.f;
        for (int i = t; i < 1536; i += 256) s += partials[q * 1536 + i];
        red[t] = s;
        __syncthreads();
        for (int o = 128; o; o >>= 1) {
            if (t < o) red[t] += red[t + o];
            __syncthreads();
        }
        if (t == 0) loss_acc += red[0] / (float)(M_ * C_);
        __syncthreads();
    }
    for (int q = 0; q < Q_; ++q) {
        float s = 0.f;
        for (int k = t; k < K_; k += 256) {
            float p = (float)counts[q * K_ + k] / (float)M_;
            s += p * logf(p + 1e-10f);
        }
        red[t] = s;
        __syncthreads();
        for (int o = 128; o; o >>= 1) {
            if (t < o) red[t] += red[t + o];
            __syncthreads();
        }
        if (t == 0) perp_acc += expf(-red[0]);
        __syncthreads();
    }
    if (t == 0) {
        out[OUT_LOSS] = loss_acc / (float)Q_;
        out[OUT_PERP] = perp_acc / (float)Q_;
    }
}

// ---------------- quantized_out = x - res_final, back to (B,C,J,T) ----------------
__global__ __launch_bounds__(256) void final_kernel(const float* __restrict__ x,
                                                    const float* __restrict__ res,
                                                    float* __restrict__ out) {
    __shared__ float tile[32][33];
    const int tx = threadIdx.x & 31, ty = threadIdx.x >> 5;
    const int jt0 = blockIdx.x * 32;
    const int c0 = blockIdx.y * 32;
    const int b = blockIdx.z;
    const float* rb = res + ((size_t)b * JT + jt0) * C_ + c0;
    #pragma unroll
    for (int i = 0; i < 4; ++i) {
        int jj = ty + 8 * i;
        tile[jj][tx] = rb[(size_t)jj * C_ + tx];
    }
    __syncthreads();
    const float* xb = x + ((size_t)b * C_ + c0) * JT + jt0;
    float* ob = out + ((size_t)b * C_ + c0) * JT + jt0;
    #pragma unroll
    for (int i = 0; i < 4; ++i) {
        int cc = ty + 8 * i;
        ob[(size_t)cc * JT + tx] = xb[(size_t)cc * JT + tx] - tile[tx][cc];
    }
}

// ---------------- indices (B,J,T,Q) as float ----------------
__global__ __launch_bounds__(256) void idxout_kernel(const int* __restrict__ idxin,
                                                     float* __restrict__ out) {
    int f = blockIdx.x * 256 + threadIdx.x;
    if (f >= M_ * Q_) return;
    int m = f / Q_;
    int q = f - m * Q_;
    out[f] = (float)idxin[q * M_ + m];
}

extern "C" void kernel_launch(void* const* d_in, const int* in_sizes, int n_in,
                              void* d_out, int out_size, void* d_ws, size_t ws_size,
                              hipStream_t stream) {
    const float* x = (const float*)d_in[0];
    const float* cb = (const float*)d_in[1];
    float* out = (float*)d_out;
    char* ws = (char*)d_ws;

    float* res = (float*)ws;                               // 50,331,648 B
    int* idxws = (int*)(ws + 50331648);                    //  2,359,296 B
    float* c2 = (float*)(ws + 52690944);                   //     24,576 B
    int* counts = (int*)(ws + 52715520);                   //     24,576 B
    float* partials = (float*)(ws + 52740096);             //     36,864 B
    unsigned short* cb_h = (unsigned short*)(ws + 52776960);   // 1,572,864 B
    unsigned short* cb_l = (unsigned short*)(ws + 54349824);   // 1,572,864 B

    hipMemsetAsync(counts, 0, Q_ * K_ * sizeof(int), stream);
    c2_kernel<<<1536, 256, 0, stream>>>(cb, c2);
    cbsplit_kernel<<<3072, 256, 0, stream>>>(cb, cb_h, cb_l);
    transpose_kernel<<<dim3(96, 4, 32), 256, 0, stream>>>(x, res);
    for (int q = 0; q < Q_; ++q) {
        vq_stage_kernel<<<1536, 256, 0, stream>>>(res, cb, cb_h, cb_l, c2,
                                                  idxws, counts, partials, q);
    }
    scalars_kernel<<<1, 256, 0, stream>>>(partials, counts, out);
    final_kernel<<<dim3(96, 4, 32), 256, 0, stream>>>(x, res, out);
    idxout_kernel<<<2304, 256, 0, stream>>>(idxws, out + OUT_IDX);
}

// Round 4
// 1300.233 us; speedup vs baseline: 2.7373x; 2.7373x over previous
//
#include <hip/hip_runtime.h>

typedef __attribute__((ext_vector_type(8))) short short8v;
typedef __attribute__((ext_vector_type(4))) float f32x4;

#define B_ 32
#define C_ 128
#define J_ 24
#define T_ 128
#define Q_ 6
#define K_ 1024
#define JT (J_*T_)          // 3072
#define M_ (B_*JT)          // 98304
#define NBLK 768            // M_/128 rows per block

#define OUT_QUANT 0
#define OUT_IDX   12582912
#define OUT_LOSS  13172736
#define OUT_PERP  13172737

#define TAU 0.02f

__device__ __forceinline__ unsigned short f2bf(float f) {
    unsigned int u = __float_as_uint(f);
    u = (u + 0x7FFFu + ((u >> 16) & 1u)) >> 16;
    return (unsigned short)u;
}
__device__ __forceinline__ float bf2f(unsigned short h) {
    return __uint_as_float(((unsigned int)h) << 16);
}

__device__ __forceinline__ void gload16(const void* g, void* lds) {
    __builtin_amdgcn_global_load_lds(
        (const __attribute__((address_space(1))) void*)g,
        (__attribute__((address_space(3))) void*)lds, 16, 0, 0);
}

// ---------------- c2: per-code squared norms (fp32 codebook) ----------------
__global__ __launch_bounds__(256) void c2_kernel(const float* __restrict__ cb,
                                                 float* __restrict__ c2) {
    int wave = (blockIdx.x * blockDim.x + threadIdx.x) >> 6;
    int lane = threadIdx.x & 63;
    if (wave >= Q_ * K_) return;
    const float2 v = reinterpret_cast<const float2*>(cb + (size_t)wave * C_)[lane];
    float s = v.x * v.x + v.y * v.y;
    #pragma unroll
    for (int off = 32; off; off >>= 1) s += __shfl_down(s, off, 64);
    if (lane == 0) c2[wave] = s;
}

// ---------------- codebook -> tiled/swizzled bf16 hi/lo LDS-image layout ----------------
// chunk index i = ((q*32 + tau)*1024 + slot); slot = part*512 + ks*128 + nt*64
//                 + a*16 + (c4&8) + ((c4&7)^a);  code = tau*32 + nt*16 + c4
// chunk data = halves [ks*32 + a*8, +8) of code row, part 0 = hi, 1 = lo.
__global__ __launch_bounds__(256) void cbtile_kernel(const float* __restrict__ cb,
                                                     unsigned short* __restrict__ cbt) {
    int i = blockIdx.x * 256 + threadIdx.x;
    if (i >= Q_ * 32 * 1024) return;
    int q = i >> 15;
    int rem = i & 32767;
    int tau = rem >> 10;
    int slot = rem & 1023;
    int part = slot >> 9;
    int ks = (slot >> 7) & 3;
    int nt = (slot >> 6) & 1;
    int r6 = slot & 63;
    int a = (r6 >> 4) & 3;
    int b3 = (r6 >> 3) & 1;
    int low3 = r6 & 7;
    int c4 = (b3 << 3) | (low3 ^ a);
    int code = tau * 32 + nt * 16 + c4;
    const float* src = cb + ((size_t)q * K_ + code) * C_ + ks * 32 + a * 8;
    short8v v;
    #pragma unroll
    for (int j = 0; j < 8; ++j) {
        float f = src[j];
        unsigned short hh = f2bf(f);
        v[j] = (part == 0) ? (short)hh : (short)f2bf(f - bf2f(hh));
    }
    *(short8v*)(cbt + (size_t)i * 8) = v;
}

// ---------------- transpose x (B,C,J,T) -> res (M,C) ----------------
__global__ __launch_bounds__(256) void transpose_kernel(const float* __restrict__ x,
                                                        float* __restrict__ res) {
    __shared__ float tile[32][33];
    const int tx = threadIdx.x & 31, ty = threadIdx.x >> 5;
    const int jt0 = blockIdx.x * 32;
    const int c0 = blockIdx.y * 32;
    const int b = blockIdx.z;
    const float* xb = x + ((size_t)b * C_ + c0) * JT + jt0;
    #pragma unroll
    for (int i = 0; i < 4; ++i) {
        int cc = ty + 8 * i;
        tile[cc][tx] = xb[(size_t)cc * JT + tx];
    }
    __syncthreads();
    float* rb = res + ((size_t)b * JT + jt0) * C_ + c0;
    #pragma unroll
    for (int i = 0; i < 4; ++i) {
        int jj = ty + 8 * i;
        rb[(size_t)jj * C_ + tx] = tile[tx][jj];
    }
}

// ---------------- fused VQ stage: MFMA argmin + fp64 refine + update ----------------
__global__ __launch_bounds__(256, 2) void vq_stage_kernel(
        float* __restrict__ res, const float* __restrict__ cb,
        const unsigned short* __restrict__ cbt, const float* __restrict__ c2g,
        int* __restrict__ idxws, int* __restrict__ counts,
        float* __restrict__ partials, int q) {
    __shared__ __attribute__((aligned(16))) unsigned short bstage[2][8192]; // 2 x 16 KB
    __shared__ float r2_lds[128];
    __shared__ int idx_lds[128];
    __shared__ int nflag[4];
    __shared__ int flagl[4][32];
    __shared__ float wsum[4];

    const int t = threadIdx.x;
    const int w = t >> 6, l = t & 63;
    const int la = l >> 4;        // 0..3
    const int lc = l & 15;
    const int rowbase = blockIdx.x * 128 + w * 32;
    const int lb = la * 256 + (l & 8) * 16 + (((l & 7) ^ la) * 16); // frag-read byte base

    if (l == 0) nflag[w] = 0;

    // ---- issue stage of tile 0 ----
    {
        const unsigned short* sp = cbt + ((size_t)(q * 32 + 0)) * 8192 + w * 2048 + l * 8;
        char* dp = ((char*)bstage[0]) + w * 4096;
        gload16(sp, dp);
        gload16(sp + 512, dp + 1024);
        gload16(sp + 1024, dp + 2048);
        gload16(sp + 1536, dp + 3072);
    }

    // ---- A fragments: res rows -> bf16 hi/lo in regs; row sqnorm partials ----
    short8v ah[2][4], al[2][4];
    float r2p[2] = {0.f, 0.f};
    #pragma unroll
    for (int mf = 0; mf < 2; ++mf) {
        const float* ap = res + (size_t)(rowbase + mf * 16 + lc) * C_ + la * 8;
        #pragma unroll
        for (int ks = 0; ks < 4; ++ks) {
            float4 f0 = *(const float4*)(ap + ks * 32);
            float4 f1 = *(const float4*)(ap + ks * 32 + 4);
            short8v vh, vl;
#define CNV(slot, val) { float _v = (val); r2p[mf] += _v * _v; unsigned short _h = f2bf(_v); \
                         vh[slot] = (short)_h; vl[slot] = (short)f2bf(_v - bf2f(_h)); }
            CNV(0, f0.x) CNV(1, f0.y) CNV(2, f0.z) CNV(3, f0.w)
            CNV(4, f1.x) CNV(5, f1.y) CNV(6, f1.z) CNV(7, f1.w)
#undef CNV
            ah[mf][ks] = vh;
            al[mf][ks] = vl;
        }
        r2p[mf] += __shfl_xor(r2p[mf], 16);
        r2p[mf] += __shfl_xor(r2p[mf], 32);
    }
    if (l < 16) {
        r2_lds[w * 32 + lc] = r2p[0];
        r2_lds[w * 32 + 16 + lc] = r2p[1];
    }
    float r2v[2][4];
    #pragma unroll
    for (int mf = 0; mf < 2; ++mf)
        #pragma unroll
        for (int rg = 0; rg < 4; ++rg)
            r2v[mf][rg] = r2_lds[w * 32 + mf * 16 + la * 4 + rg];

    float bd[2][4], bd2[2][4];
    int bi[2][4];
    #pragma unroll
    for (int mf = 0; mf < 2; ++mf)
        #pragma unroll
        for (int rg = 0; rg < 4; ++rg) { bd[mf][rg] = 3.4e38f; bd2[mf][rg] = 3.4e38f; bi[mf][rg] = 0; }

    __syncthreads();   // tile 0 staged (drains vmcnt), r2_lds visible

    // ---- main loop: 32 tiles of 32 codes ----
    for (int tau = 0; tau < 32; ++tau) {
        const char* bufp = (const char*)bstage[tau & 1];
        if (tau < 31) {
            const unsigned short* sp = cbt + ((size_t)(q * 32 + tau + 1)) * 8192 + w * 2048 + l * 8;
            char* dp = ((char*)bstage[(tau & 1) ^ 1]) + w * 4096;
            gload16(sp, dp);
            gload16(sp + 512, dp + 1024);
            gload16(sp + 1024, dp + 2048);
            gload16(sp + 1536, dp + 3072);
        }
        #pragma unroll
        for (int nt = 0; nt < 2; ++nt) {
            const int code = tau * 32 + nt * 16 + lc;
            const float c2v = c2g[q * K_ + code];
            f32x4 aA0 = {0.f,0.f,0.f,0.f}, aB0 = aA0, aC0 = aA0;
            f32x4 aA1 = aA0, aB1 = aA0, aC1 = aA0;
            #pragma unroll
            for (int ks = 0; ks < 4; ++ks) {
                const char* bb = bufp + ks * 2048 + nt * 1024 + lb;
                const short8v bh = *(const short8v*)(bb);
                const short8v bl = *(const short8v*)(bb + 8192);
                aA0 = __builtin_amdgcn_mfma_f32_16x16x32_bf16(ah[0][ks], bh, aA0, 0, 0, 0);
                aB0 = __builtin_amdgcn_mfma_f32_16x16x32_bf16(al[0][ks], bh, aB0, 0, 0, 0);
                aC0 = __builtin_amdgcn_mfma_f32_16x16x32_bf16(ah[0][ks], bl, aC0, 0, 0, 0);
                aA1 = __builtin_amdgcn_mfma_f32_16x16x32_bf16(ah[1][ks], bh, aA1, 0, 0, 0);
                aB1 = __builtin_amdgcn_mfma_f32_16x16x32_bf16(al[1][ks], bh, aB1, 0, 0, 0);
                aC1 = __builtin_amdgcn_mfma_f32_16x16x32_bf16(ah[1][ks], bl, aC1, 0, 0, 0);
            }
#define UPD(A, Bv, Cv, mf, rg) { \
            float s = (A[rg] + Bv[rg]) + Cv[rg]; \
            float d = fmaf(-2.f, s, r2v[mf][rg]) + c2v; \
            bool lt = d < bd[mf][rg]; \
            bd2[mf][rg] = lt ? bd[mf][rg] : fminf(bd2[mf][rg], d); \
            bd[mf][rg] = lt ? d : bd[mf][rg]; \
            bi[mf][rg] = lt ? code : bi[mf][rg]; }
            UPD(aA0, aB0, aC0, 0, 0) UPD(aA0, aB0, aC0, 0, 1)
            UPD(aA0, aB0, aC0, 0, 2) UPD(aA0, aB0, aC0, 0, 3)
            UPD(aA1, aB1, aC1, 1, 0) UPD(aA1, aB1, aC1, 1, 1)
            UPD(aA1, aB1, aC1, 1, 2) UPD(aA1, aB1, aC1, 1, 3)
#undef UPD
        }
        __syncthreads();
    }

    // ---- per-wave cross-lane argmin reduce (16 code-lanes per row) ----
    #pragma unroll
    for (int mf = 0; mf < 2; ++mf) {
        #pragma unroll
        for (int rg = 0; rg < 4; ++rg) {
            float d1 = bd[mf][rg], d2 = bd2[mf][rg];
            int i1 = bi[mf][rg];
            #pragma unroll
            for (int off = 1; off < 16; off <<= 1) {
                float od1 = __shfl_xor(d1, off);
                float od2 = __shfl_xor(d2, off);
                int oi1 = __shfl_xor(i1, off);
                float nd2 = fminf(fminf(d2, od2), fmaxf(d1, od1));
                if (od1 < d1 || (od1 == d1 && oi1 < i1)) { d1 = od1; i1 = oi1; }
                d2 = nd2;
            }
            if (lc == 0) {
                const int rr = mf * 16 + la * 4 + rg;    // row within wave, 0..31
                idx_lds[w * 32 + rr] = i1;
                if (d2 - d1 < TAU) {
                    int p = atomicAdd(&nflag[w], 1);
                    flagl[w][p] = rr;
                }
            }
        }
    }

    // ---- fp64 refinement (wave-local, rare) ----
    {
        const int nf = nflag[w];
        for (int f = 0; f < nf; ++f) {
            const int rr = flagl[w][f];
            const float4* rp4 = (const float4*)(res + (size_t)(rowbase + rr) * C_);
            double bdd = 1e300;
            int bk = 0;
            for (int kk = 0; kk < 16; ++kk) {
                const int k = l + kk * 64;
                const float4* bp4 = (const float4*)(cb + ((size_t)q * K_ + k) * C_);
                double s = 0.0;
                for (int c4 = 0; c4 < 32; ++c4) {
                    float4 bv = bp4[c4];
                    float4 rv = rp4[c4];
                    double d0 = (double)rv.x - (double)bv.x; s = fma(d0, d0, s);
                    double d1 = (double)rv.y - (double)bv.y; s = fma(d1, d1, s);
                    double d2 = (double)rv.z - (double)bv.z; s = fma(d2, d2, s);
                    double d3 = (double)rv.w - (double)bv.w; s = fma(d3, d3, s);
                }
                if (s < bdd || (s == bdd && k < bk)) { bdd = s; bk = k; }
            }
            #pragma unroll
            for (int off = 1; off < 64; off <<= 1) {
                double od = __shfl_xor(bdd, off);
                int ok = __shfl_xor(bk, off);
                if (od < bdd || (od == bdd && ok < bk)) { bdd = od; bk = ok; }
            }
            if (l == 0) idx_lds[w * 32 + rr] = bk;
        }
    }

    // ---- idx out + histogram ----
    if (l < 16) {
        const int k0 = idx_lds[w * 32 + l];
        const int k1 = idx_lds[w * 32 + 16 + l];
        idxws[(size_t)q * M_ + rowbase + l] = k0;
        idxws[(size_t)q * M_ + rowbase + 16 + l] = k1;
        atomicAdd(&counts[q * K_ + k0], 1);
        atomicAdd(&counts[q * K_ + k1], 1);
    }

    // ---- fused update: residual, loss partial (wave-local rows) ----
    float sq = 0.f;
    #pragma unroll
    for (int mf = 0; mf < 2; ++mf) {
        const int k = idx_lds[w * 32 + mf * 16 + lc];
        const float* cbr = cb + ((size_t)q * K_ + k) * C_ + la * 8;
        float* ap = res + (size_t)(rowbase + mf * 16 + lc) * C_ + la * 8;
        #pragma unroll
        for (int ks = 0; ks < 4; ++ks) {
            #pragma unroll
            for (int h = 0; h < 2; ++h) {
                float4 rv = *(const float4*)(ap + ks * 32 + h * 4);
                float4 cv = *(const float4*)(cbr + ks * 32 + h * 4);
                float dx = rv.x - cv.x, dy = rv.y - cv.y, dz = rv.z - cv.z, dw = rv.w - cv.w;
                sq += dx * dx + dy * dy + dz * dz + dw * dw;
                float4 nr;
                nr.x = rv.x - (rv.x + (cv.x - rv.x));
                nr.y = rv.y - (rv.y + (cv.y - rv.y));
                nr.z = rv.z - (rv.z + (cv.z - rv.z));
                nr.w = rv.w - (rv.w + (cv.w - rv.w));
                *(float4*)(ap + ks * 32 + h * 4) = nr;
            }
        }
    }
    #pragma unroll
    for (int off = 32; off; off >>= 1) sq += __shfl_down(sq, off, 64);
    if (l == 0) wsum[w] = sq;
    __syncthreads();
    if (t == 0) partials[q * NBLK + blockIdx.x] = wsum[0] + wsum[1] + wsum[2] + wsum[3];
}

// ---------------- scalars: loss + perplexity ----------------
__global__ __launch_bounds__(256) void scalars_kernel(const float* __restrict__ partials,
                                                      const int* __restrict__ counts,
                                                      float* __restrict__ out) {
    __shared__ float red[256];
    const int t = threadIdx.x;
    float loss_acc = 0.f, perp_acc = 0.f;
    for (int q = 0; q < Q_; ++q) {
        float s = 0.f;
        for (int i = t; i < NBLK; i += 256) s += partials[q * NBLK + i];
        red[t] = s;
        __syncthreads();
        for (int o = 128; o; o >>= 1) {
            if (t < o) red[t] += red[t + o];
            __syncthreads();
        }
        if (t == 0) loss_acc += red[0] / (float)(M_ * C_);
        __syncthreads();
    }
    for (int q = 0; q < Q_; ++q) {
        float s = 0.f;
        for (int k = t; k < K_; k += 256) {
            float p = (float)counts[q * K_ + k] / (float)M_;
            s += p * logf(p + 1e-10f);
        }
        red[t] = s;
        __syncthreads();
        for (int o = 128; o; o >>= 1) {
            if (t < o) red[t] += red[t + o];
            __syncthreads();
        }
        if (t == 0) perp_acc += expf(-red[0]);
        __syncthreads();
    }
    if (t == 0) {
        out[OUT_LOSS] = loss_acc / (float)Q_;
        out[OUT_PERP] = perp_acc / (float)Q_;
    }
}

// ---------------- quantized_out = x - res_final, back to (B,C,J,T) ----------------
__global__ __launch_bounds__(256) void final_kernel(const float* __restrict__ x,
                                                    const float* __restrict__ res,
                                                    float* __restrict__ out) {
    __shared__ float tile[32][33];
    const int tx = threadIdx.x & 31, ty = threadIdx.x >> 5;
    const int jt0 = blockIdx.x * 32;
    const int c0 = blockIdx.y * 32;
    const int b = blockIdx.z;
    const float* rb = res + ((size_t)b * JT + jt0) * C_ + c0;
    #pragma unroll
    for (int i = 0; i < 4; ++i) {
        int jj = ty + 8 * i;
        tile[jj][tx] = rb[(size_t)jj * C_ + tx];
    }
    __syncthreads();
    const float* xb = x + ((size_t)b * C_ + c0) * JT + jt0;
    float* ob = out + ((size_t)b * C_ + c0) * JT + jt0;
    #pragma unroll
    for (int i = 0; i < 4; ++i) {
        int cc = ty + 8 * i;
        ob[(size_t)cc * JT + tx] = xb[(size_t)cc * JT + tx] - tile[tx][cc];
    }
}

// ---------------- indices (B,J,T,Q) as float ----------------
__global__ __launch_bounds__(256) void idxout_kernel(const int* __restrict__ idxin,
                                                     float* __restrict__ out) {
    int f = blockIdx.x * 256 + threadIdx.x;
    if (f >= M_ * Q_) return;
    int m = f / Q_;
    int q = f - m * Q_;
    out[f] = (float)idxin[q * M_ + m];
}

extern "C" void kernel_launch(void* const* d_in, const int* in_sizes, int n_in,
                              void* d_out, int out_size, void* d_ws, size_t ws_size,
                              hipStream_t stream) {
    const float* x = (const float*)d_in[0];
    const float* cb = (const float*)d_in[1];
    float* out = (float*)d_out;
    char* ws = (char*)d_ws;

    float* res = (float*)ws;                               // 50,331,648 B
    int* idxws = (int*)(ws + 50331648);                    //  2,359,296 B
    float* c2 = (float*)(ws + 52690944);                   //     24,576 B
    int* counts = (int*)(ws + 52715520);                   //     24,576 B
    float* partials = (float*)(ws + 52740096);             //     18,432 B
    unsigned short* cbt = (unsigned short*)(ws + 52758528);// 3,145,728 B

    hipMemsetAsync(counts, 0, Q_ * K_ * sizeof(int), stream);
    c2_kernel<<<1536, 256, 0, stream>>>(cb, c2);
    cbtile_kernel<<<768, 256, 0, stream>>>(cb, cbt);
    transpose_kernel<<<dim3(96, 4, 32), 256, 0, stream>>>(x, res);
    for (int q = 0; q < Q_; ++q) {
        vq_stage_kernel<<<NBLK, 256, 0, stream>>>(res, cb, cbt, c2,
                                                  idxws, counts, partials, q);
    }
    scalars_kernel<<<1, 256, 0, stream>>>(partials, counts, out);
    final_kernel<<<dim3(96, 4, 32), 256, 0, stream>>>(x, res, out);
    idxout_kernel<<<2304, 256, 0, stream>>>(idxws, out + OUT_IDX);
}

// Round 5
// 1164.581 us; speedup vs baseline: 3.0561x; 1.1165x over previous
//
#include <hip/hip_runtime.h>

typedef __attribute__((ext_vector_type(8))) short short8v;
typedef __attribute__((ext_vector_type(4))) float f32x4;

#define B_ 32
#define C_ 128
#define J_ 24
#define T_ 128
#define Q_ 6
#define K_ 1024
#define JT (J_*T_)          // 3072
#define M_ (B_*JT)          // 98304
#define NBLK 768            // M_/128 rows per block

#define OUT_QUANT 0
#define OUT_IDX   12582912
#define OUT_LOSS  13172736
#define OUT_PERP  13172737

#define TAU 0.02f

__device__ __forceinline__ unsigned short f2bf(float f) {
    unsigned int u = __float_as_uint(f);
    u = (u + 0x7FFFu + ((u >> 16) & 1u)) >> 16;
    return (unsigned short)u;
}
__device__ __forceinline__ float bf2f(unsigned short h) {
    return __uint_as_float(((unsigned int)h) << 16);
}

__device__ __forceinline__ void gload16(const void* g, void* lds) {
    __builtin_amdgcn_global_load_lds(
        (const __attribute__((address_space(1))) void*)g,
        (__attribute__((address_space(3))) void*)lds, 16, 0, 0);
}

// ---------------- c2: per-code squared norms (fp32 codebook) ----------------
__global__ __launch_bounds__(256) void c2_kernel(const float* __restrict__ cb,
                                                 float* __restrict__ c2) {
    int wave = (blockIdx.x * blockDim.x + threadIdx.x) >> 6;
    int lane = threadIdx.x & 63;
    if (wave >= Q_ * K_) return;
    const float2 v = reinterpret_cast<const float2*>(cb + (size_t)wave * C_)[lane];
    float s = v.x * v.x + v.y * v.y;
    #pragma unroll
    for (int off = 32; off; off >>= 1) s += __shfl_down(s, off, 64);
    if (lane == 0) c2[wave] = s;
}

// ---------------- codebook -> tiled/swizzled bf16 hi/lo LDS-image layout ----------------
__global__ __launch_bounds__(256) void cbtile_kernel(const float* __restrict__ cb,
                                                     unsigned short* __restrict__ cbt) {
    int i = blockIdx.x * 256 + threadIdx.x;
    if (i >= Q_ * 32 * 1024) return;
    int q = i >> 15;
    int rem = i & 32767;
    int tau = rem >> 10;
    int slot = rem & 1023;
    int part = slot >> 9;
    int ks = (slot >> 7) & 3;
    int nt = (slot >> 6) & 1;
    int r6 = slot & 63;
    int a = (r6 >> 4) & 3;
    int b3 = (r6 >> 3) & 1;
    int low3 = r6 & 7;
    int c4 = (b3 << 3) | (low3 ^ a);
    int code = tau * 32 + nt * 16 + c4;
    const float* src = cb + ((size_t)q * K_ + code) * C_ + ks * 32 + a * 8;
    short8v v;
    #pragma unroll
    for (int j = 0; j < 8; ++j) {
        float f = src[j];
        unsigned short hh = f2bf(f);
        v[j] = (part == 0) ? (short)hh : (short)f2bf(f - bf2f(hh));
    }
    *(short8v*)(cbt + (size_t)i * 8) = v;
}

// ---------------- transpose x (B,C,J,T) -> res (M,C) ----------------
__global__ __launch_bounds__(256) void transpose_kernel(const float* __restrict__ x,
                                                        float* __restrict__ res) {
    __shared__ float tile[32][33];
    const int tx = threadIdx.x & 31, ty = threadIdx.x >> 5;
    const int jt0 = blockIdx.x * 32;
    const int c0 = blockIdx.y * 32;
    const int b = blockIdx.z;
    const float* xb = x + ((size_t)b * C_ + c0) * JT + jt0;
    #pragma unroll
    for (int i = 0; i < 4; ++i) {
        int cc = ty + 8 * i;
        tile[cc][tx] = xb[(size_t)cc * JT + tx];
    }
    __syncthreads();
    float* rb = res + ((size_t)b * JT + jt0) * C_ + c0;
    #pragma unroll
    for (int i = 0; i < 4; ++i) {
        int jj = ty + 8 * i;
        rb[(size_t)jj * C_ + tx] = tile[tx][jj];
    }
}

// ---------------- fused VQ stage: MFMA argmin + fp64 refine + update ----------------
__global__ __launch_bounds__(256, 3) void vq_stage_kernel(
        float* __restrict__ res, const float* __restrict__ cb,
        const unsigned short* __restrict__ cbt, const float* __restrict__ c2g,
        int* __restrict__ idxws, int* __restrict__ counts,
        float* __restrict__ partials, int q) {
    __shared__ __attribute__((aligned(16))) unsigned short bs0[8192]; // 16 KB
    __shared__ __attribute__((aligned(16))) unsigned short bs1[8192];
    __shared__ __attribute__((aligned(16))) unsigned short bs2[8192];
    __shared__ int idx_lds[128];
    __shared__ int nflag[4];
    __shared__ int flagl[4][32];
    __shared__ float wsum[4];

    const int t = threadIdx.x;
    const int w = t >> 6, l = t & 63;
    const int la = l >> 4;        // 0..3
    const int lc = l & 15;
    const int rowbase = blockIdx.x * 128 + w * 32;
    const int lb = la * 256 + (l & 8) * 16 + (((l & 7) ^ la) * 16); // frag-read byte base

    if (l == 0) nflag[w] = 0;

    const unsigned short* cbase = cbt + (size_t)q * (32 * 8192);

#define STAGE(tau_, buf_) { \
        const unsigned short* sp = cbase + (size_t)(tau_) * 8192 + w * 2048 + l * 8; \
        char* dp = ((char*)(buf_)) + w * 4096 + l * 16; \
        gload16(sp, dp); \
        gload16(sp + 512, dp + 1024 - l * 16 + l * 16); \
        gload16(sp + 1024, dp + 2048); \
        gload16(sp + 1536, dp + 3072); \
    }
    // (dp already includes l*16; gload16 adds lane offset itself via hardware: dest is
    //  wave-uniform base + lane*16, so pass base without l*16)
#undef STAGE
#define STAGE(tau_, buf_) { \
        const unsigned short* sp = cbase + (size_t)(tau_) * 8192 + w * 2048 + l * 8; \
        char* dp = ((char*)(buf_)) + w * 4096; \
        gload16(sp, dp); \
        gload16(sp + 512, dp + 1024); \
        gload16(sp + 1024, dp + 2048); \
        gload16(sp + 1536, dp + 3072); \
    }

    // ---- prologue: stage tiles 0 and 1 ----
    STAGE(0, bs0)
    STAGE(1, bs1)

    // ---- A fragments: res rows -> bf16 hi/lo in regs ----
    short8v ah[2][4], al[2][4];
    #pragma unroll
    for (int mf = 0; mf < 2; ++mf) {
        const float* ap = res + (size_t)(rowbase + mf * 16 + lc) * C_ + la * 8;
        #pragma unroll
        for (int ks = 0; ks < 4; ++ks) {
            float4 f0 = *(const float4*)(ap + ks * 32);
            float4 f1 = *(const float4*)(ap + ks * 32 + 4);
            short8v vh, vl;
#define CNV(slot, val) { float _v = (val); unsigned short _h = f2bf(_v); \
                         vh[slot] = (short)_h; vl[slot] = (short)f2bf(_v - bf2f(_h)); }
            CNV(0, f0.x) CNV(1, f0.y) CNV(2, f0.z) CNV(3, f0.w)
            CNV(4, f1.x) CNV(5, f1.y) CNV(6, f1.z) CNV(7, f1.w)
#undef CNV
            ah[mf][ks] = vh;
            al[mf][ks] = vl;
        }
    }

    float bd[2][4], bd2[2][4];
    int bi[2][4];
    #pragma unroll
    for (int mf = 0; mf < 2; ++mf)
        #pragma unroll
        for (int rg = 0; rg < 4; ++rg) { bd[mf][rg] = 3.4e38f; bd2[mf][rg] = 3.4e38f; bi[mf][rg] = 0; }

    __syncthreads();   // tiles 0,1 staged (full drain), nflag visible

    const char* bcur = (const char*)bs0;
    const char* bnx1 = (const char*)bs1;
    const char* bnx2 = (const char*)bs2;
    const int qk0 = q * K_;

    // ---- main loop: 32 tiles of 32 codes; counted-vmcnt pipeline ----
    for (int tau = 0; tau < 32; ++tau) {
        // c2 loads first (issue-order matters for vmcnt accounting)
        const float c2v0 = c2g[qk0 + tau * 32 + lc];
        const float c2v1 = c2g[qk0 + tau * 32 + 16 + lc];
        if (tau < 30) STAGE(tau + 2, (void*)bnx2)

        #pragma unroll
        for (int nt = 0; nt < 2; ++nt) {
            const int code = tau * 32 + nt * 16 + lc;
            const float c2v = nt ? c2v1 : c2v0;
            f32x4 aA0 = {0.f,0.f,0.f,0.f}, aM0 = aA0, aA1 = aA0, aM1 = aA0;
            #pragma unroll
            for (int ks = 0; ks < 4; ++ks) {
                const char* bb = bcur + ks * 2048 + nt * 1024 + lb;
                const short8v bh = *(const short8v*)(bb);
                const short8v bl = *(const short8v*)(bb + 8192);
                aA0 = __builtin_amdgcn_mfma_f32_16x16x32_bf16(ah[0][ks], bh, aA0, 0, 0, 0);
                aM0 = __builtin_amdgcn_mfma_f32_16x16x32_bf16(al[0][ks], bh, aM0, 0, 0, 0);
                aM0 = __builtin_amdgcn_mfma_f32_16x16x32_bf16(ah[0][ks], bl, aM0, 0, 0, 0);
                aA1 = __builtin_amdgcn_mfma_f32_16x16x32_bf16(ah[1][ks], bh, aA1, 0, 0, 0);
                aM1 = __builtin_amdgcn_mfma_f32_16x16x32_bf16(al[1][ks], bh, aM1, 0, 0, 0);
                aM1 = __builtin_amdgcn_mfma_f32_16x16x32_bf16(ah[1][ks], bl, aM1, 0, 0, 0);
            }
#define UPD(A, Mv, mf, rg) { \
            float s = A[rg] + Mv[rg]; \
            float d = fmaf(-2.f, s, c2v); \
            bool lt = d < bd[mf][rg]; \
            bd2[mf][rg] = lt ? bd[mf][rg] : fminf(bd2[mf][rg], d); \
            bd[mf][rg] = lt ? d : bd[mf][rg]; \
            bi[mf][rg] = lt ? code : bi[mf][rg]; }
            UPD(aA0, aM0, 0, 0) UPD(aA0, aM0, 0, 1) UPD(aA0, aM0, 0, 2) UPD(aA0, aM0, 0, 3)
            UPD(aA1, aM1, 1, 0) UPD(aA1, aM1, 1, 1) UPD(aA1, aM1, 1, 2) UPD(aA1, aM1, 1, 3)
#undef UPD
        }

        // partial drain: my tile-(tau+1) loads are older than this iter's 6 ops -> done at <=4
        if (tau < 30) {
            asm volatile("s_waitcnt vmcnt(4)" ::: "memory");
        } else {
            asm volatile("s_waitcnt vmcnt(0)" ::: "memory");
        }
        __builtin_amdgcn_s_barrier();
        const char* tmp = bcur; bcur = bnx1; bnx1 = bnx2; bnx2 = tmp;
    }

    // ---- per-wave cross-lane argmin reduce (16 code-lanes per row) ----
    #pragma unroll
    for (int mf = 0; mf < 2; ++mf) {
        #pragma unroll
        for (int rg = 0; rg < 4; ++rg) {
            float d1 = bd[mf][rg], d2 = bd2[mf][rg];
            int i1 = bi[mf][rg];
            #pragma unroll
            for (int off = 1; off < 16; off <<= 1) {
                float od1 = __shfl_xor(d1, off);
                float od2 = __shfl_xor(d2, off);
                int oi1 = __shfl_xor(i1, off);
                float nd2 = fminf(fminf(d2, od2), fmaxf(d1, od1));
                if (od1 < d1 || (od1 == d1 && oi1 < i1)) { d1 = od1; i1 = oi1; }
                d2 = nd2;
            }
            if (lc == 0) {
                const int rr = mf * 16 + la * 4 + rg;    // row within wave, 0..31
                idx_lds[w * 32 + rr] = i1;
                if (d2 - d1 < TAU) {
                    int p = atomicAdd(&nflag[w], 1);
                    flagl[w][p] = rr;
                }
            }
        }
    }

    // ---- fp64 refinement (wave-local, rare) ----
    {
        const int nf = nflag[w];
        for (int f = 0; f < nf; ++f) {
            const int rr = flagl[w][f];
            const float4* rp4 = (const float4*)(res + (size_t)(rowbase + rr) * C_);
            double bdd = 1e300;
            int bk = 0;
            for (int kk = 0; kk < 16; ++kk) {
                const int k = l + kk * 64;
                const float4* bp4 = (const float4*)(cb + ((size_t)q * K_ + k) * C_);
                double s = 0.0;
                for (int c4 = 0; c4 < 32; ++c4) {
                    float4 bv = bp4[c4];
                    float4 rv = rp4[c4];
                    double d0 = (double)rv.x - (double)bv.x; s = fma(d0, d0, s);
                    double d1 = (double)rv.y - (double)bv.y; s = fma(d1, d1, s);
                    double d2 = (double)rv.z - (double)bv.z; s = fma(d2, d2, s);
                    double d3 = (double)rv.w - (double)bv.w; s = fma(d3, d3, s);
                }
                if (s < bdd || (s == bdd && k < bk)) { bdd = s; bk = k; }
            }
            #pragma unroll
            for (int off = 1; off < 64; off <<= 1) {
                double od = __shfl_xor(bdd, off);
                int ok = __shfl_xor(bk, off);
                if (od < bdd || (od == bdd && ok < bk)) { bdd = od; bk = ok; }
            }
            if (l == 0) idx_lds[w * 32 + rr] = bk;
        }
    }

    // ---- idx out + histogram ----
    if (l < 16) {
        const int k0 = idx_lds[w * 32 + l];
        const int k1 = idx_lds[w * 32 + 16 + l];
        idxws[(size_t)q * M_ + rowbase + l] = k0;
        idxws[(size_t)q * M_ + rowbase + 16 + l] = k1;
        atomicAdd(&counts[q * K_ + k0], 1);
        atomicAdd(&counts[q * K_ + k1], 1);
    }

    // ---- fused update: residual, loss partial (wave-local rows) ----
    float sq = 0.f;
    #pragma unroll
    for (int mf = 0; mf < 2; ++mf) {
        const int k = idx_lds[w * 32 + mf * 16 + lc];
        const float* cbr = cb + ((size_t)q * K_ + k) * C_ + la * 8;
        float* ap = res + (size_t)(rowbase + mf * 16 + lc) * C_ + la * 8;
        #pragma unroll
        for (int ks = 0; ks < 4; ++ks) {
            #pragma unroll
            for (int h = 0; h < 2; ++h) {
                float4 rv = *(const float4*)(ap + ks * 32 + h * 4);
                float4 cv = *(const float4*)(cbr + ks * 32 + h * 4);
                float dx = rv.x - cv.x, dy = rv.y - cv.y, dz = rv.z - cv.z, dw = rv.w - cv.w;
                sq += dx * dx + dy * dy + dz * dz + dw * dw;
                float4 nr;
                nr.x = rv.x - (rv.x + (cv.x - rv.x));
                nr.y = rv.y - (rv.y + (cv.y - rv.y));
                nr.z = rv.z - (rv.z + (cv.z - rv.z));
                nr.w = rv.w - (rv.w + (cv.w - rv.w));
                *(float4*)(ap + ks * 32 + h * 4) = nr;
            }
        }
    }
    #pragma unroll
    for (int off = 32; off; off >>= 1) sq += __shfl_down(sq, off, 64);
    if (l == 0) wsum[w] = sq;
    __syncthreads();
    if (t == 0) partials[q * NBLK + blockIdx.x] = wsum[0] + wsum[1] + wsum[2] + wsum[3];
#undef STAGE
}

// ---------------- scalars: loss + perplexity ----------------
__global__ __launch_bounds__(256) void scalars_kernel(const float* __restrict__ partials,
                                                      const int* __restrict__ counts,
                                                      float* __restrict__ out) {
    __shared__ float red[256];
    const int t = threadIdx.x;
    float loss_acc = 0.f, perp_acc = 0.f;
    for (int q = 0; q < Q_; ++q) {
        float s = 0.f;
        for (int i = t; i < NBLK; i += 256) s += partials[q * NBLK + i];
        red[t] = s;
        __syncthreads();
        for (int o = 128; o; o >>= 1) {
            if (t < o) red[t] += red[t + o];
            __syncthreads();
        }
        if (t == 0) loss_acc += red[0] / (float)(M_ * C_);
        __syncthreads();
    }
    for (int q = 0; q < Q_; ++q) {
        float s = 0.f;
        for (int k = t; k < K_; k += 256) {
            float p = (float)counts[q * K_ + k] / (float)M_;
            s += p * logf(p + 1e-10f);
        }
        red[t] = s;
        __syncthreads();
        for (int o = 128; o; o >>= 1) {
            if (t < o) red[t] += red[t + o];
            __syncthreads();
        }
        if (t == 0) perp_acc += expf(-red[0]);
        __syncthreads();
    }
    if (t == 0) {
        out[OUT_LOSS] = loss_acc / (float)Q_;
        out[OUT_PERP] = perp_acc / (float)Q_;
    }
}

// ---------------- quantized_out = x - res_final, back to (B,C,J,T) ----------------
__global__ __launch_bounds__(256) void final_kernel(const float* __restrict__ x,
                                                    const float* __restrict__ res,
                                                    float* __restrict__ out) {
    __shared__ float tile[32][33];
    const int tx = threadIdx.x & 31, ty = threadIdx.x >> 5;
    const int jt0 = blockIdx.x * 32;
    const int c0 = blockIdx.y * 32;
    const int b = blockIdx.z;
    const float* rb = res + ((size_t)b * JT + jt0) * C_ + c0;
    #pragma unroll
    for (int i = 0; i < 4; ++i) {
        int jj = ty + 8 * i;
        tile[jj][tx] = rb[(size_t)jj * C_ + tx];
    }
    __syncthreads();
    const float* xb = x + ((size_t)b * C_ + c0) * JT + jt0;
    float* ob = out + ((size_t)b * C_ + c0) * JT + jt0;
    #pragma unroll
    for (int i = 0; i < 4; ++i) {
        int cc = ty + 8 * i;
        ob[(size_t)cc * JT + tx] = xb[(size_t)cc * JT + tx] - tile[tx][cc];
    }
}

// ---------------- indices (B,J,T,Q) as float ----------------
__global__ __launch_bounds__(256) void idxout_kernel(const int* __restrict__ idxin,
                                                     float* __restrict__ out) {
    int f = blockIdx.x * 256 + threadIdx.x;
    if (f >= M_ * Q_) return;
    int m = f / Q_;
    int q = f - m * Q_;
    out[f] = (float)idxin[q * M_ + m];
}

extern "C" void kernel_launch(void* const* d_in, const int* in_sizes, int n_in,
                              void* d_out, int out_size, void* d_ws, size_t ws_size,
                              hipStream_t stream) {
    const float* x = (const float*)d_in[0];
    const float* cb = (const float*)d_in[1];
    float* out = (float*)d_out;
    char* ws = (char*)d_ws;

    float* res = (float*)ws;                               // 50,331,648 B
    int* idxws = (int*)(ws + 50331648);                    //  2,359,296 B
    float* c2 = (float*)(ws + 52690944);                   //     24,576 B
    int* counts = (int*)(ws + 52715520);                   //     24,576 B
    float* partials = (float*)(ws + 52740096);             //     18,432 B
    unsigned short* cbt = (unsigned short*)(ws + 52758528);// 3,145,728 B

    hipMemsetAsync(counts, 0, Q_ * K_ * sizeof(int), stream);
    c2_kernel<<<1536, 256, 0, stream>>>(cb, c2);
    cbtile_kernel<<<768, 256, 0, stream>>>(cb, cbt);
    transpose_kernel<<<dim3(96, 4, 32), 256, 0, stream>>>(x, res);
    for (int q = 0; q < Q_; ++q) {
        vq_stage_kernel<<<NBLK, 256, 0, stream>>>(res, cb, cbt, c2,
                                                  idxws, counts, partials, q);
    }
    scalars_kernel<<<1, 256, 0, stream>>>(partials, counts, out);
    final_kernel<<<dim3(96, 4, 32), 256, 0, stream>>>(x, res, out);
    idxout_kernel<<<2304, 256, 0, stream>>>(idxws, out + OUT_IDX);
}